// Round 1
// 232.757 us; speedup vs baseline: 1.0720x; 1.0720x over previous
//
#include <hip/hip_runtime.h>
#include <hip/hip_bf16.h>

typedef __bf16 bf16;
typedef __bf16 bf16x8 __attribute__((ext_vector_type(8)));
typedef float floatx4 __attribute__((ext_vector_type(4)));

// B=2, T=512, C=8, D=512, H=8, dk=64. M = B*T*C = 8192.
// Inputs fp32 (dict order), output fp32.
// ws regions (R = 8192*512 bf16 = 8.39 MB): r0 r1 r2 r3 | WT (2 MB) = 35.6 MB
// Chain: wtr -> WT ; gemm_qkv (fp32 A direct, z=3 merged):
//   q->r0 (Q, pre-scaled 0.125, [hd][t][d]), k->r1 (K, [hd][t][d]),
//   v->r2 (V^T, [hd][d][t]) ; attn (r0,r1,r2)->r3 ; out-gemm r3 -> d_out.

#define AS1 __attribute__((address_space(1)))
#define AS3 __attribute__((address_space(3)))

__device__ __forceinline__ void gload_lds16(const bf16* g, bf16* l) {
    __builtin_amdgcn_global_load_lds((const AS1 unsigned int*)g,
                                     (AS3 unsigned int*)l, 16, 0, 0);
}

union Pack8 { bf16 h[8]; uint4 u; };

// ---------------- weight transpose W[K][N] fp32 -> WT[N][K] bf16 -------------
__global__ __launch_bounds__(256) void wtr_kernel(
    const float* __restrict__ Wq, const float* __restrict__ Wk,
    const float* __restrict__ Wv, const float* __restrict__ Wo,
    bf16* __restrict__ WT)
{
    __shared__ float Ts[64][65];
    const int tid = threadIdx.x;
    const int k0 = blockIdx.x * 64;
    const int n0 = blockIdx.y * 64;
    const int z  = blockIdx.z;
    const float* W = (z == 0) ? Wq : (z == 1) ? Wk : (z == 2) ? Wv : Wo;
    bf16* O = WT + (size_t)z * 512 * 512;
    #pragma unroll
    for (int i = 0; i < 16; i++) {
        const int r = i * 4 + (tid >> 6), c = tid & 63;
        Ts[r][c] = W[(size_t)(k0 + r) * 512 + n0 + c];
    }
    __syncthreads();
    #pragma unroll
    for (int i = 0; i < 16; i++) {
        const int a = i * 4 + (tid >> 6), c = tid & 63;
        O[(size_t)(n0 + a) * 512 + k0 + c] = (bf16)Ts[c][a];
    }
}

// ---------------- merged Q/K/V projection GEMM, fp32 A read + convert --------
// A [8192][512] fp32 (selected by z), BT [512][512] bf16 k-major via
// global_load_lds. Block 256 = 4 waves, wave = 64x64 quadrant, acc[4][4].
// z=0: Q -> [hd][t][d], scaled 0.125 (folds softmax 1/sqrt(dk));
// z=1: K -> [hd][t][d]; z=2: V^T -> [hd][d][t].
__global__ __launch_bounds__(256) void gemm_qkv(
    const float* __restrict__ Aq, const float* __restrict__ Ak,
    const float* __restrict__ Av, const bf16* __restrict__ WT,
    const float* __restrict__ Bq, const float* __restrict__ Bk,
    const float* __restrict__ Bv,
    bf16* __restrict__ Oq, bf16* __restrict__ Ok, bf16* __restrict__ Ov)
{
    __shared__ bf16 Asm[128 * 32];
    __shared__ bf16 Bsm[128 * 32];
    const int z = blockIdx.z;
    const float* A    = (z == 0) ? Aq : (z == 1) ? Ak : Av;
    const float* bias = (z == 0) ? Bq : (z == 1) ? Bk : Bv;
    bf16* out         = (z == 0) ? Oq : (z == 1) ? Ok : Ov;
    const bf16* BT = WT + (size_t)z * 262144;
    const float scale = (z == 0) ? 0.125f : 1.0f;

    const int tid  = threadIdx.x;
    const int lane = tid & 63;
    const int wave = tid >> 6;
    const int quad = lane >> 4;
    const int l16  = lane & 15;
    const int mblk = blockIdx.x * 128;
    const int nblk = blockIdx.y * 128;

    // staging rows: wave w covers rows [w*16, w*16+16) and [64+w*16, ...).
    // lane i -> row +i/4, col (i&3)*8 (same layout the lds-DMA scatter makes).
    const int srow = wave * 16 + (lane >> 2);
    const int scol = (lane & 3) * 8;
    const float* Ag0 = A + (size_t)(mblk + srow) * 512 + scol;
    const float* Ag1 = Ag0 + (size_t)64 * 512;
    const bf16* Bg0 = BT + (size_t)(nblk + srow) * 512 + scol;
    const bf16* Bg1 = Bg0 + (size_t)64 * 512;
    bf16* Alp0 = Asm + srow * 32 + scol;   // per-lane LDS write addr
    bf16* Alp1 = Alp0 + 64 * 32;
    bf16* Bl0 = Bsm + wave * 16 * 32;      // wave-uniform base for lds-DMA
    bf16* Bl1 = Bsm + (64 + wave * 16) * 32;

    const int wr = (wave >> 1) * 64;
    const int wc = (wave & 1) * 64;

    floatx4 acc[4][4] = {};
    for (int k0 = 0; k0 < 512; k0 += 32) {
        gload_lds16(Bg0 + k0, Bl0);
        gload_lds16(Bg1 + k0, Bl1);
        float4 x0 = *(const float4*)(Ag0 + k0);
        float4 x1 = *(const float4*)(Ag0 + k0 + 4);
        float4 y0 = *(const float4*)(Ag1 + k0);
        float4 y1 = *(const float4*)(Ag1 + k0 + 4);
        Pack8 pa, pb;
        pa.h[0] = (bf16)x0.x; pa.h[1] = (bf16)x0.y;
        pa.h[2] = (bf16)x0.z; pa.h[3] = (bf16)x0.w;
        pa.h[4] = (bf16)x1.x; pa.h[5] = (bf16)x1.y;
        pa.h[6] = (bf16)x1.z; pa.h[7] = (bf16)x1.w;
        pb.h[0] = (bf16)y0.x; pb.h[1] = (bf16)y0.y;
        pb.h[2] = (bf16)y0.z; pb.h[3] = (bf16)y0.w;
        pb.h[4] = (bf16)y1.x; pb.h[5] = (bf16)y1.y;
        pb.h[6] = (bf16)y1.z; pb.h[7] = (bf16)y1.w;
        *(uint4*)Alp0 = pa.u;
        *(uint4*)Alp1 = pb.u;
        __syncthreads();
        bf16x8 a[4], b[4];
        #pragma unroll
        for (int mt = 0; mt < 4; mt++)
            a[mt] = *(const bf16x8*)(Asm + (wr + mt * 16 + l16) * 32 + quad * 8);
        #pragma unroll
        for (int nt = 0; nt < 4; nt++)
            b[nt] = *(const bf16x8*)(Bsm + (wc + nt * 16 + l16) * 32 + quad * 8);
        #pragma unroll
        for (int mt = 0; mt < 4; mt++)
            #pragma unroll
            for (int nt = 0; nt < 4; nt++)
                acc[mt][nt] = __builtin_amdgcn_mfma_f32_16x16x32_bf16(
                    a[mt], b[nt], acc[mt][nt], 0, 0, 0);
        __syncthreads();
    }

    #pragma unroll
    for (int mt = 0; mt < 4; mt++) {
        #pragma unroll
        for (int nt = 0; nt < 4; nt++) {
            const int colg = nblk + wc + nt * 16 + l16;
            const float bb = bias[colg];
            #pragma unroll
            for (int r = 0; r < 4; r++) {
                const int rowg = mblk + wr + mt * 16 + quad * 4 + r;
                const float v = (acc[mt][nt][r] + bb) * scale;
                const int b_ = rowg >> 12;
                const int t = (rowg >> 3) & 511;
                const int c = rowg & 7;
                const int h = colg >> 6;
                const int d = colg & 63;
                const int hd = b_ * 64 + h * 8 + c;
                const size_t addr = (z == 2)
                    ? ((size_t)hd * 64 + d) * 512 + t
                    : ((size_t)hd * 512 + t) * 64 + d;
                out[addr] = (bf16)v;
            }
        }
    }
}

// ---------------- m97-style GEMM for output projection (layout 2) ------------
template<int LAYOUT, typename TO>
__global__ __launch_bounds__(256) void gemm_bt(
    const bf16* __restrict__ A, const bf16* __restrict__ BT,
    const float* __restrict__ bias, TO* __restrict__ out)
{
    __shared__ bf16 Asm[128 * 32];
    __shared__ bf16 Bsm[128 * 32];
    const int tid  = threadIdx.x;
    const int lane = tid & 63;
    const int wave = tid >> 6;
    const int quad = lane >> 4;
    const int l16  = lane & 15;
    const int mblk = blockIdx.x * 128;
    const int nblk = blockIdx.y * 128;

    const int srow = wave * 16 + (lane >> 2);
    const int scol = (lane & 3) * 8;
    const bf16* Ag0 = A + (size_t)(mblk + srow) * 512 + scol;
    const bf16* Ag1 = Ag0 + (size_t)64 * 512;
    const bf16* Bg0 = BT + (size_t)(nblk + srow) * 512 + scol;
    const bf16* Bg1 = Bg0 + (size_t)64 * 512;
    bf16* Al0 = Asm + wave * 16 * 32;
    bf16* Al1 = Asm + (64 + wave * 16) * 32;
    bf16* Bl0 = Bsm + wave * 16 * 32;
    bf16* Bl1 = Bsm + (64 + wave * 16) * 32;

    const int wr = (wave >> 1) * 64;
    const int wc = (wave & 1) * 64;

    floatx4 acc[4][4] = {};
    for (int k0 = 0; k0 < 512; k0 += 32) {
        gload_lds16(Ag0 + k0, Al0);
        gload_lds16(Ag1 + k0, Al1);
        gload_lds16(Bg0 + k0, Bl0);
        gload_lds16(Bg1 + k0, Bl1);
        __syncthreads();
        bf16x8 a[4], b[4];
        #pragma unroll
        for (int mt = 0; mt < 4; mt++)
            a[mt] = *(const bf16x8*)(Asm + (wr + mt * 16 + l16) * 32 + quad * 8);
        #pragma unroll
        for (int nt = 0; nt < 4; nt++)
            b[nt] = *(const bf16x8*)(Bsm + (wc + nt * 16 + l16) * 32 + quad * 8);
        #pragma unroll
        for (int mt = 0; mt < 4; mt++)
            #pragma unroll
            for (int nt = 0; nt < 4; nt++)
                acc[mt][nt] = __builtin_amdgcn_mfma_f32_16x16x32_bf16(
                    a[mt], b[nt], acc[mt][nt], 0, 0, 0);
        __syncthreads();
    }

    #pragma unroll
    for (int mt = 0; mt < 4; mt++) {
        #pragma unroll
        for (int nt = 0; nt < 4; nt++) {
            const int colg = nblk + wc + nt * 16 + l16;
            const float bb = bias[colg];
            #pragma unroll
            for (int r = 0; r < 4; r++) {
                const int rowg = mblk + wr + mt * 16 + quad * 4 + r;
                const float v = acc[mt][nt][r] + bb;
                if (LAYOUT == 2) {
                    out[(size_t)rowg * 512 + colg] = (TO)v;
                } else {
                    const int b_ = rowg >> 12;
                    const int t = (rowg >> 3) & 511;
                    const int c = rowg & 7;
                    const int h = colg >> 6;
                    const int d = colg & 63;
                    const int hd = b_ * 64 + h * 8 + c;
                    const size_t addr = (LAYOUT == 0)
                        ? ((size_t)hd * 512 + t) * 64 + d
                        : ((size_t)hd * 64 + d) * 512 + t;
                    out[addr] = (TO)v;
                }
            }
        }
    }
}

// ---------------- attention ---------------------------------------------------
// Changes vs prev: (a) Msm/Psm aliased into one buffer (lifetimes disjoint:
// last mask read before redM barrier, first P write after redS barrier) ->
// LDS 33.8K -> 17.2K -> 8 blocks/CU; (b) flat grid + XCD swizzle so each XCD
// owns 16 heads (K/V L2-resident); (c) 0.125 scale pre-folded into Q.
#define PST 520

__global__ __launch_bounds__(256, 8) void attn_kernel(
    const bf16* __restrict__ Qws, const bf16* __restrict__ Kws,
    const bf16* __restrict__ Vtws, const int* __restrict__ mask,
    bf16* __restrict__ Xws)
{
    __shared__ bf16 MPsm[16][PST];   // mask (phase 1) then P (phase 2)
    __shared__ float redM[4][16];
    __shared__ float redS[4][16];
    const int tid  = threadIdx.x;
    const int wave = tid >> 6;
    const int lane = tid & 63;
    const int quad = lane >> 4;
    const int l16  = lane & 15;
    // XCD swizzle: dispatch slot s -> o = (s&7)*512 + s/8. XCD x gets heads
    // [x*16, x*16+16) exclusively; qt varies fastest within an XCD.
    const int s_ = blockIdx.x;
    const int o_ = ((s_ & 7) << 9) | (s_ >> 3);
    const int qt = o_ & 31;
    const int hd = o_ >> 5;
    const int q0 = qt * 16;
    const int b = hd >> 6;
    const int h = (hd >> 3) & 7;
    const int c = hd & 7;

    {
        const int* mp = mask + ((size_t)b * 512 + q0) * 512;
        #pragma unroll
        for (int it = 0; it < 8; it++) {
            const int idx = (it * 256 + tid) * 4;
            const int4 mv = *(const int4*)(mp + idx);
            const int row = idx >> 9, col = idx & 511;
            union { bf16 h[4]; unsigned long long u; } pk;
            pk.h[0] = (mv.x == 0) ? (bf16)(-1.0e9f) : (bf16)0.0f;
            pk.h[1] = (mv.y == 0) ? (bf16)(-1.0e9f) : (bf16)0.0f;
            pk.h[2] = (mv.z == 0) ? (bf16)(-1.0e9f) : (bf16)0.0f;
            pk.h[3] = (mv.w == 0) ? (bf16)(-1.0e9f) : (bf16)0.0f;
            *(unsigned long long*)&MPsm[row][col] = pk.u;
        }
    }

    const bf16* Qh = Qws + (size_t)hd * 512 * 64;
    const bf16* Kh = Kws + (size_t)hd * 512 * 64;
    bf16x8 aq0 = *(const bf16x8*)(Qh + (size_t)(q0 + l16) * 64 + quad * 8);
    bf16x8 aq1 = *(const bf16x8*)(Qh + (size_t)(q0 + l16) * 64 + 32 + quad * 8);
    __syncthreads();

    float sv[8][4];
    float mx[4] = {-3.0e38f, -3.0e38f, -3.0e38f, -3.0e38f};
    #pragma unroll
    for (int nt = 0; nt < 8; nt++) {
        const int s0 = wave * 128 + nt * 16;
        bf16x8 bk0 = *(const bf16x8*)(Kh + (size_t)(s0 + l16) * 64 + quad * 8);
        bf16x8 bk1 = *(const bf16x8*)(Kh + (size_t)(s0 + l16) * 64 + 32 + quad * 8);
        floatx4 s = {};
        s = __builtin_amdgcn_mfma_f32_16x16x32_bf16(aq0, bk0, s, 0, 0, 0);
        s = __builtin_amdgcn_mfma_f32_16x16x32_bf16(aq1, bk1, s, 0, 0, 0);
        #pragma unroll
        for (int r = 0; r < 4; r++) {
            const float v = s[r] + (float)MPsm[quad * 4 + r][s0 + l16];
            sv[nt][r] = v;
            mx[r] = fmaxf(mx[r], v);
        }
    }
    #pragma unroll
    for (int off = 1; off < 16; off <<= 1)
        #pragma unroll
        for (int r = 0; r < 4; r++)
            mx[r] = fmaxf(mx[r], __shfl_xor(mx[r], off, 64));
    if (l16 == 0)
        #pragma unroll
        for (int r = 0; r < 4; r++) redM[wave][quad * 4 + r] = mx[r];
    __syncthreads();
    float mf[4], sum[4] = {0.f, 0.f, 0.f, 0.f};
    #pragma unroll
    for (int r = 0; r < 4; r++) {
        const int qr = quad * 4 + r;
        mf[r] = fmaxf(fmaxf(redM[0][qr], redM[1][qr]),
                      fmaxf(redM[2][qr], redM[3][qr]));
    }
    #pragma unroll
    for (int nt = 0; nt < 8; nt++)
        #pragma unroll
        for (int r = 0; r < 4; r++) {
            const float e = __expf(sv[nt][r] - mf[r]);
            sv[nt][r] = e;
            sum[r] += e;
        }
    #pragma unroll
    for (int off = 1; off < 16; off <<= 1)
        #pragma unroll
        for (int r = 0; r < 4; r++)
            sum[r] += __shfl_xor(sum[r], off, 64);
    if (l16 == 0)
        #pragma unroll
        for (int r = 0; r < 4; r++) redS[wave][quad * 4 + r] = sum[r];
    __syncthreads();
    float inv[4];
    #pragma unroll
    for (int r = 0; r < 4; r++) {
        const int qr = quad * 4 + r;
        inv[r] = 1.f / (redS[0][qr] + redS[1][qr] + redS[2][qr] + redS[3][qr]);
    }
    #pragma unroll
    for (int nt = 0; nt < 8; nt++)
        #pragma unroll
        for (int r = 0; r < 4; r++)
            MPsm[quad * 4 + r][wave * 128 + nt * 16 + l16] =
                (bf16)(sv[nt][r] * inv[r]);
    __syncthreads();

    const bf16* Vh = Vtws + (size_t)hd * 64 * 512;
    const int d0 = wave * 16;
    floatx4 oacc = {};
    #pragma unroll
    for (int ks = 0; ks < 16; ks++) {
        bf16x8 ap = *(const bf16x8*)(&MPsm[l16][ks * 32 + quad * 8]);
        bf16x8 bv = *(const bf16x8*)(Vh + (size_t)(d0 + l16) * 512 + ks * 32 + quad * 8);
        oacc = __builtin_amdgcn_mfma_f32_16x16x32_bf16(ap, bv, oacc, 0, 0, 0);
    }
    #pragma unroll
    for (int r = 0; r < 4; r++) {
        const int q = quad * 4 + r;
        const size_t row = ((size_t)b * 512 + q0 + q) * 8 + c;
        Xws[row * 512 + h * 64 + d0 + l16] = (bf16)oacc[r];
    }
}

extern "C" void kernel_launch(void* const* d_in, const int* in_sizes, int n_in,
                              void* d_out, int out_size, void* d_ws, size_t ws_size,
                              hipStream_t stream)
{
    const float* qin  = (const float*)d_in[0];
    const float* kin  = (const float*)d_in[1];
    const float* vin  = (const float*)d_in[2];
    const int*   mask = (const int*)d_in[3];
    const float* Bq = (const float*)d_in[5];
    const float* Bk = (const float*)d_in[7];
    const float* Bv = (const float*)d_in[9];
    const float* Bo = (const float*)d_in[11];
    float* out = (float*)d_out;

    const size_t R = (size_t)8192 * 512;
    bf16* r0 = (bf16*)d_ws;
    bf16* r1 = r0 + R;
    bf16* r2 = r1 + R;
    bf16* r3 = r2 + R;
    bf16* WT = r3 + R;

    wtr_kernel<<<dim3(8, 8, 4), dim3(256), 0, stream>>>(
        (const float*)d_in[4], (const float*)d_in[6],
        (const float*)d_in[8], (const float*)d_in[10], WT);
    gemm_qkv<<<dim3(64, 4, 3), dim3(256), 0, stream>>>(
        qin, kin, vin, WT, Bq, Bk, Bv, r0, r1, r2);
    attn_kernel<<<dim3(4096), dim3(256), 0, stream>>>(
        r0, r1, r2, mask, r3);
    gemm_bt<2, float><<<dim3(64, 4), dim3(256), 0, stream>>>(
        r3, WT + (size_t)3 * 262144, Bo, out);
}